// Round 16
// baseline (139.628 us; speedup 1.0000x reference)
//
#include <hip/hip_runtime.h>

#define D_  1024
#define H_  16
#define HD_ 64
#define B_  2
#define S_  2048
#define M_  (B_*S_)   // 4096

typedef _Float16 f16;
typedef _Float16 f16x8 __attribute__((ext_vector_type(8)));
typedef _Float16 f16x4 __attribute__((ext_vector_type(4)));
typedef _Float16 f16x2 __attribute__((ext_vector_type(2)));
typedef __fp16   h16x2 __attribute__((ext_vector_type(2)));
typedef float    f32x4 __attribute__((ext_vector_type(4)));

#define GLOAD_LDS16(g, l) \
  __builtin_amdgcn_global_load_lds((__attribute__((address_space(1))) const void*)(g), \
                                   (__attribute__((address_space(3))) void*)(l), 16, 0, 0)

// ---------------- prep: x fp32->f16 (blocks 0..4095) + 4x W transpose (4096..8191) ----------------
__global__ void k_prep(const float* __restrict__ x, f16* __restrict__ xb,
                       const float* __restrict__ Wq, const float* __restrict__ Wk,
                       const float* __restrict__ Wv, const float* __restrict__ Wo,
                       f16* __restrict__ WT) {
  __shared__ float t[32][33];
  const int bid = blockIdx.x, tid = threadIdx.x;
  if (bid < 4096) {
    int i = bid * 256 + tid;
    float4 v = ((const float4*)x)[i];
    f16x4 o = { (f16)v.x, (f16)v.y, (f16)v.z, (f16)v.w };
    ((f16x4*)xb)[i] = o;
  } else {
    int r = bid - 4096;
    const int z = r >> 10; r &= 1023;
    const int n0 = (r & 31) * 32, k0 = (r >> 5) * 32;
    const float* W = (z == 0) ? Wq : (z == 1) ? Wk : (z == 2) ? Wv : Wo;
    f16* out = WT + (size_t)z * D_ * D_;
    const int tx = tid & 31, ty = tid >> 5;
    #pragma unroll
    for (int i = 0; i < 4; i++)
      t[ty + i*8][tx] = W[(size_t)(k0 + ty + i*8) * D_ + n0 + tx];
    __syncthreads();
    #pragma unroll
    for (int i = 0; i < 4; i++)
      out[(size_t)(n0 + ty + i*8) * D_ + k0 + tx] = (f16)t[tx][ty + i*8];
  }
}

// ---------------- fused QKV GEMM (N=3072), 2-phase dbuf ----------------
__global__ __launch_bounds__(256) void k_gemm_qkv(const f16* __restrict__ A,
                                                  const f16* __restrict__ Bt,
                                                  const float* __restrict__ bq,
                                                  const float* __restrict__ bk,
                                                  const float* __restrict__ bv,
                                                  f16* __restrict__ qkv) {
  __shared__ __align__(16) f16 lA[2][128 * 32];
  __shared__ __align__(16) f16 lB[2][128 * 32];
  const int tid = threadIdx.x;
  const int wv = tid >> 6, lane = tid & 63;
  const int m0 = blockIdx.y * 128, n0 = blockIdx.x * 128;
  const float* bias = (n0 < 1024) ? bq : (n0 < 2048) ? bk : bv;
  const int fr = lane & 15, fg = lane >> 4;
  const int wm = wv >> 1, wn = wv & 1;
  const int srow = (lane >> 2), skk = (lane & 3) * 8;
  f32x4 acc[4][4] = {};

#define G_STAGE(k0_, c_) do { \
    _Pragma("unroll") \
    for (int it_ = 0; it_ < 2; ++it_) { \
      int ch_ = wv + it_ * 4; \
      int row_ = ch_ * 16 + srow; \
      GLOAD_LDS16(A  + (size_t)(m0 + row_) * D_ + (k0_) + skk, &lA[c_][ch_ * 512]); \
      GLOAD_LDS16(Bt + (size_t)(n0 + row_) * D_ + (k0_) + skk, &lB[c_][ch_ * 512]); \
    } \
  } while (0)

  G_STAGE(0, 0);
  __syncthreads();

  int c = 0;
  for (int k0 = 0; k0 < D_; k0 += 32) {
    if (k0 + 32 < D_) G_STAGE(k0 + 32, c ^ 1);
    f16x8 a[4], b[4];
    #pragma unroll
    for (int i = 0; i < 4; i++) a[i] = *(const f16x8*)&lA[c][(wm*64 + i*16 + fr) * 32 + fg * 8];
    #pragma unroll
    for (int j = 0; j < 4; j++) b[j] = *(const f16x8*)&lB[c][(wn*64 + j*16 + fr) * 32 + fg * 8];
    #pragma unroll
    for (int i = 0; i < 4; i++)
      #pragma unroll
      for (int j = 0; j < 4; j++)
        acc[i][j] = __builtin_amdgcn_mfma_f32_16x16x32_f16(a[i], b[j], acc[i][j], 0, 0, 0);
    __syncthreads();
    c ^= 1;
  }
#undef G_STAGE

  #pragma unroll
  for (int i = 0; i < 4; i++) {
    #pragma unroll
    for (int j = 0; j < 4; j++) {
      int grow0 = m0 + wm*64 + i*16 + fg*4;
      int gcol  = n0 + wn*64 + j*16 + fr;
      float bb = bias[gcol & (D_ - 1)];
      #pragma unroll
      for (int r = 0; r < 4; r++) {
        float val = acc[i][j][r] + bb;
        int grow = grow0 + r;
        int z = gcol >> 10, gl = gcol & (D_ - 1);
        int b = grow >> 11, s = grow & (S_ - 1);
        int h = gl >> 6,  hd = gl & (HD_ - 1);
        qkv[(size_t)z * (M_ * D_) + ((size_t)(b * H_ + h) * S_ + s) * HD_ + hd] = (f16)val;
      }
    }
  }
}

// ---------------- out-GEMM with FUSED COMBINE ----------------
// A[m][k] = (OA + OB)[bh][s][hd] * linv[h][row], reg-staged + ds_write into
// the same linear lA layout global_load_lds would produce. B via gload_lds.
__global__ __launch_bounds__(256) void k_gemm_out2(const f16* __restrict__ OA,
                                                   const f16* __restrict__ OB,
                                                   const float* __restrict__ la,
                                                   const float* __restrict__ lb,
                                                   const f16* __restrict__ Bt,
                                                   const float* __restrict__ bias,
                                                   float* __restrict__ Cout) {
  __shared__ __align__(16) f16 sA[2][128 * 32];
  __shared__ __align__(16) f16 sB[2][128 * 32];
  __shared__ float linv[16 * 128];
  const int tid = threadIdx.x;
  const int wv = tid >> 6, lane = tid & 63;
  const int m0 = blockIdx.y * 128, n0 = blockIdx.x * 128;
  const int fr = lane & 15, fg = lane >> 4;
  const int wm = wv >> 1, wn = wv & 1;
  const int srow = (lane >> 2), skk = (lane & 3) * 8;
  f32x4 acc[4][4] = {};

  // per-(head,row) inverse row-sums
  for (int i = tid; i < 2048; i += 256) {
    int hh = i >> 7, row = i & 127;
    int grow = m0 + row;
    size_t rowg = (size_t)((grow >> 11) * 16 + hh) * S_ + (grow & (S_ - 1));
    linv[i] = __builtin_amdgcn_rcpf(la[rowg] + lb[rowg]);
  }

  f16x8 rA[2], rB[2];

#define A_LOAD(k0_) do { \
    const int hh_ = (k0_) >> 6; \
    _Pragma("unroll") \
    for (int it_ = 0; it_ < 2; ++it_) { \
      int row_ = (wv + it_*4) * 16 + srow; \
      int grow_ = m0 + row_; \
      size_t off_ = ((size_t)((grow_ >> 11) * 16 + hh_) * S_ + (grow_ & (S_ - 1))) * HD_ \
                    + (((k0_) + skk) & (HD_ - 1)); \
      rA[it_] = *(const f16x8*)&OA[off_]; \
      rB[it_] = *(const f16x8*)&OB[off_]; \
    } \
  } while (0)

#define A_WRITE(k0_, c_) do { \
    const int hh_ = (k0_) >> 6; \
    _Pragma("unroll") \
    for (int it_ = 0; it_ < 2; ++it_) { \
      int ch_ = wv + it_*4; \
      float inv_ = linv[hh_ * 128 + ch_*16 + srow]; \
      union { f16x8 v; h16x2 h[4]; } o_; \
      _Pragma("unroll") \
      for (int j_ = 0; j_ < 4; ++j_) { \
        float e0_ = ((float)rA[it_][2*j_]   + (float)rB[it_][2*j_])   * inv_; \
        float e1_ = ((float)rA[it_][2*j_+1] + (float)rB[it_][2*j_+1]) * inv_; \
        o_.h[j_] = __builtin_amdgcn_cvt_pkrtz(e0_, e1_); \
      } \
      *(f16x8*)&sA[c_][ch_*512 + lane*8] = o_.v; \
    } \
  } while (0)

#define B_STAGE(k0_, c_) do { \
    _Pragma("unroll") \
    for (int it_ = 0; it_ < 2; ++it_) { \
      int ch_ = wv + it_*4; \
      int row_ = ch_*16 + srow; \
      GLOAD_LDS16(Bt + (size_t)(n0 + row_) * D_ + (k0_) + skk, &sB[c_][ch_*512]); \
    } \
  } while (0)

  A_LOAD(0);
  B_STAGE(0, 0);
  __syncthreads();              // linv visible
  A_WRITE(0, 0);
  __syncthreads();              // sA visible

  int c = 0;
  for (int k0 = 0; k0 < D_; k0 += 32) {
    const bool pre = (k0 + 32 < D_);
    if (pre) { A_LOAD(k0 + 32); B_STAGE(k0 + 32, c ^ 1); }
    f16x8 a[4], b[4];
    #pragma unroll
    for (int i = 0; i < 4; i++) a[i] = *(const f16x8*)&sA[c][(wm*64 + i*16 + fr) * 32 + fg * 8];
    #pragma unroll
    for (int j = 0; j < 4; j++) b[j] = *(const f16x8*)&sB[c][(wn*64 + j*16 + fr) * 32 + fg * 8];
    #pragma unroll
    for (int i = 0; i < 4; i++)
      #pragma unroll
      for (int j = 0; j < 4; j++)
        acc[i][j] = __builtin_amdgcn_mfma_f32_16x16x32_f16(a[i], b[j], acc[i][j], 0, 0, 0);
    if (pre) A_WRITE(k0 + 32, c ^ 1);   // hides under MFMA; lands before barrier
    __syncthreads();
    c ^= 1;
  }

  #pragma unroll
  for (int i = 0; i < 4; i++) {
    #pragma unroll
    for (int j = 0; j < 4; j++) {
      int grow0 = m0 + wm*64 + i*16 + fg*4;
      int gcol  = n0 + wn*64 + j*16 + fr;
      float bb = bias[gcol];
      #pragma unroll
      for (int r = 0; r < 4; r++)
        Cout[(size_t)(grow0 + r) * D_ + gcol] = acc[i][j][r] + bb;
    }
  }
#undef A_LOAD
#undef A_WRITE
#undef B_STAGE
}

// ---------------- flash attention v10 (round-14 best): unified kv schedule ----------------
#define POFF 8.65617025f   // 6 * log2(e)

__global__ __launch_bounds__(256) void k_attn(const f16* __restrict__ Qh,
                                              const f16* __restrict__ Kh,
                                              const f16* __restrict__ Vh,
                                              const int* __restrict__ am,
                                              f16* __restrict__ OpA, f16* __restrict__ OpB,
                                              float* __restrict__ lpA, float* __restrict__ lpB) {
  __shared__ __align__(16) f16 kt[2][64 * 64];     // K [k][d], XOR-swizzled
  __shared__ __align__(16) f16 vt[2][64 * 64];     // V^T [d][k], 2-level XOR-swizzled
  __shared__ __align__(16) f16 pl[4][32 * 64];     // per-wave P [qrow][k], swizzled

  const int tid = threadIdx.x;
  const int wv = tid >> 6, lane = tid & 63;
  const int fr = lane & 15, fg = lane >> 4;

  const int d = blockIdx.x;             // [0,512)
  const int bh = d & 31;
  const int m  = (d >> 5) & 7;          // pair index 0..7 -> tiles (m, 15-m)
  const int typeB = d >> 8;
  const int b = bh >> 4;

  f16*   Op = typeB ? OpB : OpA;
  float* lp = typeB ? lpB : lpA;

  const f16* Qb = Qh + (size_t)bh * S_ * HD_;
  const f16* Kb = Kh + (size_t)bh * S_ * HD_;
  const f16* Vb = Vh + (size_t)bh * S_ * HD_;
  const int* amb = am + b * S_;
  f16* plw = pl[wv];

  volatile int* flag = (volatile int*)&pl[0][0];
  if (tid == 0) *flag = 1;
  __syncthreads();
  {
    int mv = 1;
    #pragma unroll
    for (int i = 0; i < 8; ++i) mv &= amb[tid * 8 + i];
    if (!mv) *flag = 0;
  }
  __syncthreads();
  const bool allv = (*flag != 0);

  const f16 qs = (f16)0.18033688f;       // 0.125 * log2(e)
  const int ksrc = 8 * ((lane & 7) ^ (lane >> 3));
  const int swz = (fr & 7) << 3;
  const int vkk = (tid >> 3) * 2, vd0 = (tid & 7) * 8;
  const int vswz2 = (tid & 3) << 4;
  const f32x4 cinit = { -POFF, -POFF, -POFF, -POFF };
  const f16 one_ = (f16)1.0f;
  const f16x8 onesf = { one_, one_, one_, one_, one_, one_, one_, one_ };

#define STAGE_K(t_, c_) do { \
    const f16* kp_ = Kb + (size_t)((t_) * 64) * HD_; \
    GLOAD_LDS16(kp_ + (size_t)((wv*2+0)*8 + (lane >> 3)) * HD_ + ksrc, &kt[c_][(wv*2+0)*512]); \
    GLOAD_LDS16(kp_ + (size_t)((wv*2+1)*8 + (lane >> 3)) * HD_ + ksrc, &kt[c_][(wv*2+1)*512]); \
  } while (0)

#define LOAD_V(t_) do { \
    const f16* vp_ = Vb + (size_t)((t_) * 64 + vkk) * HD_ + vd0; \
    vA = *(const f16x8*)vp_; vBr = *(const f16x8*)(vp_ + HD_); \
  } while (0)

#define WRITE_V(c_) do { \
    _Pragma("unroll") \
    for (int j_ = 0; j_ < 8; ++j_) { \
      f16x2 pr_ = { vA[j_], vBr[j_] }; \
      *(f16x2*)&vt[c_][(vd0 + j_) * 64 + ((vkk ^ (j_ << 3)) ^ vswz2)] = pr_; \
    } \
  } while (0)

  f16x8 vA, vBr;

  const int qts[2] = { m, 15 - m };
  int s_t0[2], s_t1[2];
  if (!typeB) {
    s_t0[0] = 0;     s_t1[0] = m + 1;
    s_t0[1] = 0;     s_t1[1] = 16 - m;
  } else {
    s_t0[0] = m + 1;  s_t1[0] = 2 * (m + 1);
    s_t0[1] = 16 - m; s_t1[1] = 2 * (16 - m);
  }

  STAGE_K(s_t0[0], 0);
  LOAD_V(s_t0[0]);
  WRITE_V(0);
  __syncthreads();

  int c = 0;
  for (int sg = 0; sg < 2; ++sg) {
    const int qt = qts[sg];
    const int q0w = qt * 128 + wv * 32;

    f16x8 qf[2][2];
    #pragma unroll
    for (int rt = 0; rt < 2; ++rt) {
      f16x8 r0 = *(const f16x8*)&Qb[(size_t)(q0w + rt*16 + fr) * HD_ + fg*8];
      f16x8 r1 = *(const f16x8*)&Qb[(size_t)(q0w + rt*16 + fr) * HD_ + 32 + fg*8];
      qf[rt][0] = r0 * qs; qf[rt][1] = r1 * qs;
    }

    f32x4 accO[2][4] = {};
    f32x4 accL[2] = {};

    for (int t = s_t0[sg]; t < s_t1[sg]; ++t) {
      int nt_ = -1;
      if (t + 1 < s_t1[sg]) nt_ = t + 1;
      else if (sg == 0)     nt_ = s_t0[1];
      if (nt_ >= 0) { STAGE_K(nt_, c ^ 1); LOAD_V(nt_); }

      const int kb = t * 64;
      const int dq = q0w - kb;
      if (dq + 31 >= 0) {
        int tm1 = (dq + 31) >> 4; if (tm1 > 3) tm1 = 3;
        int tm0 = (dq + 15) >> 4; if (tm0 > 3) tm0 = 3;
        const bool fullb = (dq >= 63);

        f32x4 s[2][4];
        #pragma unroll
        for (int rt = 0; rt < 2; ++rt)
          #pragma unroll
          for (int tt = 0; tt < 4; ++tt) s[rt][tt] = cinit;

        __builtin_amdgcn_s_setprio(1);
        #pragma unroll
        for (int tt = 0; tt < 4; ++tt) {
          if (tt <= tm1) {
            const int kr = (tt*16 + fr) * 64;
            f16x8 kf0 = *(const f16x8*)&kt[c][kr + ((     fg*8) ^ swz)];
            f16x8 kf1 = *(const f16x8*)&kt[c][kr + ((32 + fg*8) ^ swz)];
            s[1][tt] = __builtin_amdgcn_mfma_f32_16x16x32_f16(kf0, qf[1][0], s[1][tt], 0, 0, 0);
            s[1][tt] = __builtin_amdgcn_mfma_f32_16x16x32_f16(kf1, qf[1][1], s[1][tt], 0, 0, 0);
            if (tt <= tm0) {
              s[0][tt] = __builtin_amdgcn_mfma_f32_16x16x32_f16(kf0, qf[0][0], s[0][tt], 0, 0, 0);
              s[0][tt] = __builtin_amdgcn_mfma_f32_16x16x32_f16(kf1, qf[0][1], s[0][tt], 0, 0, 0);
            }
          }
        }
        __builtin_amdgcn_s_setprio(0);

        #pragma unroll
        for (int rt = 0; rt < 2; ++rt) {
          const int tmr = rt ? tm1 : tm0;
          if (tmr < 0) continue;
          const int thr = dq + rt*16 + fr;
          #pragma unroll
          for (int tt = 0; tt < 4; ++tt) {
            union { f16x4 v; h16x2 h[2]; } pk;
            pk.v = (f16x4){};
            if (tt <= tmr) {
              float p[4];
              if (allv) {
                #pragma unroll
                for (int r = 0; r < 4; ++r) {
                  float sv = s[rt][tt][r];
                  if (!fullb) sv = (tt*16 + fg*4 + r <= thr) ? sv : -1e30f;
                  p[r] = exp2f(sv);
                }
              } else {
                int4 a4 = *(const int4*)&amb[kb + tt*16 + fg*4];
                #pragma unroll
                for (int r = 0; r < 4; ++r) {
                  float sv = s[rt][tt][r];
                  if (!fullb) sv = (tt*16 + fg*4 + r <= thr) ? sv : -1e30f;
                  float pv = exp2f(sv);
                  int mr_ = (r == 0) ? a4.x : (r == 1) ? a4.y : (r == 2) ? a4.z : a4.w;
                  p[r] = mr_ ? pv : 0.0f;
                }
              }
              pk.h[0] = __builtin_amdgcn_cvt_pkrtz(p[0], p[1]);
              pk.h[1] = __builtin_amdgcn_cvt_pkrtz(p[2], p[3]);
            }
            *(f16x4*)&plw[(rt*16 + fr) * 64 + ((tt*16 + fg*4) ^ swz)] = pk.v;
          }
        }

        __builtin_amdgcn_s_setprio(1);
        #pragma unroll
        for (int ks = 0; ks < 2; ++ks) {
          if (ks <= (tm1 >> 1)) {
            f16x8 vf[4];
            #pragma unroll
            for (int nt = 0; nt < 4; ++nt)
              vf[nt] = *(const f16x8*)&vt[c][(nt*16 + fr) * 64 +
                           ((ks*32 + fg*8) ^ swz ^ (((2*nt + (fr >> 3)) & 3) << 4))];
            #pragma unroll
            for (int rt = 0; rt < 2; ++rt) {
              const int tmr = rt ? tm1 : tm0;
              if (tmr >= 0 && ks <= (tmr >> 1)) {
                f16x8 pa = *(const f16x8*)&plw[(rt*16 + fr) * 64 + ((ks*32 + fg*8) ^ swz)];
                #pragma unroll
                for (int nt = 0; nt < 4; ++nt)
                  accO[rt][nt] = __builtin_amdgcn_mfma_f32_16x16x32_f16(pa, vf[nt], accO[rt][nt], 0, 0, 0);
                accL[rt] = __builtin_amdgcn_mfma_f32_16x16x32_f16(pa, onesf, accL[rt], 0, 0, 0);
              }
            }
          }
        }
        __builtin_amdgcn_s_setprio(0);
      }

      if (nt_ >= 0) WRITE_V(c ^ 1);
      __syncthreads();
      c ^= 1;
    }

    #pragma unroll
    for (int rt = 0; rt < 2; ++rt) {
      if (fr == 0) {
        #pragma unroll
        for (int r = 0; r < 4; ++r)
          lp[(size_t)bh * S_ + q0w + rt*16 + fg*4 + r] = accL[rt][r];
      }
      f16* Oprow = Op + (size_t)bh * (S_ * HD_);
      #pragma unroll
      for (int nt = 0; nt < 4; ++nt) {
        int col = nt*16 + fr;
        #pragma unroll
        for (int r = 0; r < 4; ++r) {
          int row = q0w + rt*16 + fg*4 + r;
          Oprow[(size_t)row * HD_ + col] = (f16)accO[rt][nt][r];
        }
      }
    }
  }

#undef STAGE_K
#undef LOAD_V
#undef WRITE_V
}

extern "C" void kernel_launch(void* const* d_in, const int* in_sizes, int n_in,
                              void* d_out, int out_size, void* d_ws, size_t ws_size,
                              hipStream_t stream) {
  const float* x  = (const float*)d_in[0];
  const int*   am = (const int*)d_in[1];
  const float* Wq = (const float*)d_in[2];
  const float* bq = (const float*)d_in[3];
  const float* Wk = (const float*)d_in[4];
  const float* bk = (const float*)d_in[5];
  const float* Wv = (const float*)d_in[6];
  const float* bv = (const float*)d_in[7];
  const float* Wo = (const float*)d_in[8];
  const float* bo = (const float*)d_in[9];

  char* ws = (char*)d_ws;
  f16*   xb  = (f16*)(ws);                      // [0,8)MB  : x f16 (dead after QKV GEMM)
  f16*   wt  = (f16*)(ws + (8u  << 20));        // [8,16)MB : 4x WT f16 (wt3 LIVE till out-GEMM)
  f16*   qkv = (f16*)(ws + (16u << 20));        // [16,40)MB: Q,K,V
  f16*   OpA = (f16*)(ws + (40u << 20));        // [40,48)MB: partial O, type A
  f16*   OpB = xb;                              // [0,8)MB  : partial O, type B (over dead xb)
  float* lpA = (float*)(ws + (8u << 20));       // over wt0 (dead after QKV)
  float* lpB = (float*)(ws + (8u << 20) + (256u << 10));

  k_prep<<<8192, 256, 0, stream>>>(x, xb, Wq, Wk, Wv, Wo, wt);

  k_gemm_qkv<<<dim3(24, 32), 256, 0, stream>>>(xb, wt, bq, bk, bv, qkv);

  k_attn<<<dim3(512), 256, 0, stream>>>(qkv,
                                        qkv + (size_t)M_ * D_,
                                        qkv + 2 * (size_t)M_ * D_,
                                        am, OpA, OpB, lpA, lpB);

  k_gemm_out2<<<dim3(8, 32), 256, 0, stream>>>(OpA, OpB, lpA, lpB,
                                               wt + 3 * (size_t)(D_ * D_), bo,
                                               (float*)d_out);
}

// Round 17
// 123.445 us; speedup vs baseline: 1.1311x; 1.1311x over previous
//
#include <hip/hip_runtime.h>

#define D_  1024
#define H_  16
#define HD_ 64
#define B_  2
#define S_  2048
#define M_  (B_*S_)   // 4096

typedef _Float16 f16;
typedef _Float16 f16x8 __attribute__((ext_vector_type(8)));
typedef _Float16 f16x4 __attribute__((ext_vector_type(4)));
typedef _Float16 f16x2 __attribute__((ext_vector_type(2)));
typedef __fp16   h16x2 __attribute__((ext_vector_type(2)));
typedef float    f32x4 __attribute__((ext_vector_type(4)));

#define GLOAD_LDS16(g, l) \
  __builtin_amdgcn_global_load_lds((__attribute__((address_space(1))) const void*)(g), \
                                   (__attribute__((address_space(3))) void*)(l), 16, 0, 0)

// ---------------- prep: x fp32->f16 (blocks 0..4095) + 4x W transpose (4096..8191) ----------------
__global__ void k_prep(const float* __restrict__ x, f16* __restrict__ xb,
                       const float* __restrict__ Wq, const float* __restrict__ Wk,
                       const float* __restrict__ Wv, const float* __restrict__ Wo,
                       f16* __restrict__ WT) {
  __shared__ float t[32][33];
  const int bid = blockIdx.x, tid = threadIdx.x;
  if (bid < 4096) {
    int i = bid * 256 + tid;
    float4 v = ((const float4*)x)[i];
    f16x4 o = { (f16)v.x, (f16)v.y, (f16)v.z, (f16)v.w };
    ((f16x4*)xb)[i] = o;
  } else {
    int r = bid - 4096;
    const int z = r >> 10; r &= 1023;
    const int n0 = (r & 31) * 32, k0 = (r >> 5) * 32;
    const float* W = (z == 0) ? Wq : (z == 1) ? Wk : (z == 2) ? Wv : Wo;
    f16* out = WT + (size_t)z * D_ * D_;
    const int tx = tid & 31, ty = tid >> 5;
    #pragma unroll
    for (int i = 0; i < 4; i++)
      t[ty + i*8][tx] = W[(size_t)(k0 + ty + i*8) * D_ + n0 + tx];
    __syncthreads();
    #pragma unroll
    for (int i = 0; i < 4; i++)
      out[(size_t)(n0 + ty + i*8) * D_ + k0 + tx] = (f16)t[tx][ty + i*8];
  }
}

// ---------------- GEMM: A[M][K] f16 @ (Bt[N][K])^T + bias, 2-phase dbuf ----------------
template<int MODE>
__device__ __forceinline__ void gemm_body(const f16* __restrict__ A,
                                          const f16* __restrict__ Bt,
                                          const float* __restrict__ bias,
                                          void* __restrict__ Cout) {
  __shared__ __align__(16) f16 lA[2][128 * 32];
  __shared__ __align__(16) f16 lB[2][128 * 32];
  const int tid = threadIdx.x;
  const int wv = tid >> 6, lane = tid & 63;
  const int m0 = blockIdx.y * 128, n0 = blockIdx.x * 128;
  const int fr = lane & 15, fg = lane >> 4;
  const int wm = wv >> 1, wn = wv & 1;
  const int srow = (lane >> 2), skk = (lane & 3) * 8;
  f32x4 acc[4][4] = {};

#define G_STAGE(k0_, c_) do { \
    _Pragma("unroll") \
    for (int it_ = 0; it_ < 2; ++it_) { \
      int ch_ = wv + it_ * 4; \
      int row_ = ch_ * 16 + srow; \
      GLOAD_LDS16(A  + (size_t)(m0 + row_) * D_ + (k0_) + skk, &lA[c_][ch_ * 512]); \
      GLOAD_LDS16(Bt + (size_t)(n0 + row_) * D_ + (k0_) + skk, &lB[c_][ch_ * 512]); \
    } \
  } while (0)

  G_STAGE(0, 0);
  __syncthreads();

  int c = 0;
  for (int k0 = 0; k0 < D_; k0 += 32) {
    if (k0 + 32 < D_) G_STAGE(k0 + 32, c ^ 1);
    f16x8 a[4], b[4];
    #pragma unroll
    for (int i = 0; i < 4; i++) a[i] = *(const f16x8*)&lA[c][(wm*64 + i*16 + fr) * 32 + fg * 8];
    #pragma unroll
    for (int j = 0; j < 4; j++) b[j] = *(const f16x8*)&lB[c][(wn*64 + j*16 + fr) * 32 + fg * 8];
    #pragma unroll
    for (int i = 0; i < 4; i++)
      #pragma unroll
      for (int j = 0; j < 4; j++)
        acc[i][j] = __builtin_amdgcn_mfma_f32_16x16x32_f16(a[i], b[j], acc[i][j], 0, 0, 0);
    __syncthreads();
    c ^= 1;
  }
#undef G_STAGE

  #pragma unroll
  for (int i = 0; i < 4; i++) {
    #pragma unroll
    for (int j = 0; j < 4; j++) {
      int grow0 = m0 + wm*64 + i*16 + fg*4;
      int gcol  = n0 + wn*64 + j*16 + fr;
      float bb = bias[gcol & (D_ - 1)];
      #pragma unroll
      for (int r = 0; r < 4; r++) {
        float val = acc[i][j][r] + bb;
        int grow = grow0 + r;
        if (MODE == 0) {
          int z = gcol >> 10, gl = gcol & (D_ - 1);
          int b = grow >> 11, s = grow & (S_ - 1);
          int h = gl >> 6,  hd = gl & (HD_ - 1);
          ((f16*)Cout)[(size_t)z * (M_ * D_) +
                       ((size_t)(b * H_ + h) * S_ + s) * HD_ + hd] = (f16)val;
        } else {
          ((float*)Cout)[(size_t)grow * D_ + gcol] = val;
        }
      }
    }
  }
}

__global__ __launch_bounds__(256) void k_gemm_qkv(const f16* __restrict__ A,
                                                  const f16* __restrict__ WT0,
                                                  const float* __restrict__ bq,
                                                  const float* __restrict__ bk,
                                                  const float* __restrict__ bv,
                                                  f16* __restrict__ qkv) {
  const int n0 = blockIdx.x * 128;
  const float* bias = (n0 < 1024) ? bq : (n0 < 2048) ? bk : bv;
  gemm_body<0>(A, WT0, bias, qkv);
}

__global__ __launch_bounds__(256) void k_gemm_out(const f16* __restrict__ A,
                                                  const f16* __restrict__ Bt,
                                                  const float* __restrict__ bias,
                                                  float* __restrict__ Cout) {
  gemm_body<1>(A, Bt, bias, Cout);
}

// ---------------- flash attention v10 (best measured): unified kv schedule ----------------
#define POFF 8.65617025f   // 6 * log2(e)

__global__ __launch_bounds__(256) void k_attn(const f16* __restrict__ Qh,
                                              const f16* __restrict__ Kh,
                                              const f16* __restrict__ Vh,
                                              const int* __restrict__ am,
                                              f16* __restrict__ OpA, f16* __restrict__ OpB,
                                              float* __restrict__ lpA, float* __restrict__ lpB) {
  __shared__ __align__(16) f16 kt[2][64 * 64];     // K [k][d], XOR-swizzled
  __shared__ __align__(16) f16 vt[2][64 * 64];     // V^T [d][k], 2-level XOR-swizzled
  __shared__ __align__(16) f16 pl[4][32 * 64];     // per-wave P [qrow][k], swizzled

  const int tid = threadIdx.x;
  const int wv = tid >> 6, lane = tid & 63;
  const int fr = lane & 15, fg = lane >> 4;

  const int d = blockIdx.x;             // [0,512)
  const int bh = d & 31;
  const int m  = (d >> 5) & 7;          // pair index 0..7 -> tiles (m, 15-m)
  const int typeB = d >> 8;
  const int b = bh >> 4;

  f16*   Op = typeB ? OpB : OpA;
  float* lp = typeB ? lpB : lpA;

  const f16* Qb = Qh + (size_t)bh * S_ * HD_;
  const f16* Kb = Kh + (size_t)bh * S_ * HD_;
  const f16* Vb = Vh + (size_t)bh * S_ * HD_;
  const int* amb = am + b * S_;
  f16* plw = pl[wv];

  volatile int* flag = (volatile int*)&pl[0][0];
  if (tid == 0) *flag = 1;
  __syncthreads();
  {
    int mv = 1;
    #pragma unroll
    for (int i = 0; i < 8; ++i) mv &= amb[tid * 8 + i];
    if (!mv) *flag = 0;
  }
  __syncthreads();
  const bool allv = (*flag != 0);

  const f16 qs = (f16)0.18033688f;       // 0.125 * log2(e)
  const int ksrc = 8 * ((lane & 7) ^ (lane >> 3));
  const int swz = (fr & 7) << 3;
  const int vkk = (tid >> 3) * 2, vd0 = (tid & 7) * 8;
  const int vswz2 = (tid & 3) << 4;
  const f32x4 cinit = { -POFF, -POFF, -POFF, -POFF };
  const f16 one_ = (f16)1.0f;
  const f16x8 onesf = { one_, one_, one_, one_, one_, one_, one_, one_ };

#define STAGE_K(t_, c_) do { \
    const f16* kp_ = Kb + (size_t)((t_) * 64) * HD_; \
    GLOAD_LDS16(kp_ + (size_t)((wv*2+0)*8 + (lane >> 3)) * HD_ + ksrc, &kt[c_][(wv*2+0)*512]); \
    GLOAD_LDS16(kp_ + (size_t)((wv*2+1)*8 + (lane >> 3)) * HD_ + ksrc, &kt[c_][(wv*2+1)*512]); \
  } while (0)

#define LOAD_V(t_) do { \
    const f16* vp_ = Vb + (size_t)((t_) * 64 + vkk) * HD_ + vd0; \
    vA = *(const f16x8*)vp_; vBr = *(const f16x8*)(vp_ + HD_); \
  } while (0)

#define WRITE_V(c_) do { \
    _Pragma("unroll") \
    for (int j_ = 0; j_ < 8; ++j_) { \
      f16x2 pr_ = { vA[j_], vBr[j_] }; \
      *(f16x2*)&vt[c_][(vd0 + j_) * 64 + ((vkk ^ (j_ << 3)) ^ vswz2)] = pr_; \
    } \
  } while (0)

  f16x8 vA, vBr;

  const int qts[2] = { m, 15 - m };
  int s_t0[2], s_t1[2];
  if (!typeB) {
    s_t0[0] = 0;     s_t1[0] = m + 1;
    s_t0[1] = 0;     s_t1[1] = 16 - m;
  } else {
    s_t0[0] = m + 1;  s_t1[0] = 2 * (m + 1);
    s_t0[1] = 16 - m; s_t1[1] = 2 * (16 - m);
  }

  STAGE_K(s_t0[0], 0);
  LOAD_V(s_t0[0]);
  WRITE_V(0);
  __syncthreads();

  int c = 0;
  for (int sg = 0; sg < 2; ++sg) {
    const int qt = qts[sg];
    const int q0w = qt * 128 + wv * 32;

    f16x8 qf[2][2];
    #pragma unroll
    for (int rt = 0; rt < 2; ++rt) {
      f16x8 r0 = *(const f16x8*)&Qb[(size_t)(q0w + rt*16 + fr) * HD_ + fg*8];
      f16x8 r1 = *(const f16x8*)&Qb[(size_t)(q0w + rt*16 + fr) * HD_ + 32 + fg*8];
      qf[rt][0] = r0 * qs; qf[rt][1] = r1 * qs;
    }

    f32x4 accO[2][4] = {};
    f32x4 accL[2] = {};

    for (int t = s_t0[sg]; t < s_t1[sg]; ++t) {
      int nt_ = -1;
      if (t + 1 < s_t1[sg]) nt_ = t + 1;
      else if (sg == 0)     nt_ = s_t0[1];
      if (nt_ >= 0) { STAGE_K(nt_, c ^ 1); LOAD_V(nt_); }

      const int kb = t * 64;
      const int dq = q0w - kb;
      if (dq + 31 >= 0) {
        int tm1 = (dq + 31) >> 4; if (tm1 > 3) tm1 = 3;
        int tm0 = (dq + 15) >> 4; if (tm0 > 3) tm0 = 3;
        const bool fullb = (dq >= 63);

        f32x4 s[2][4];
        #pragma unroll
        for (int rt = 0; rt < 2; ++rt)
          #pragma unroll
          for (int tt = 0; tt < 4; ++tt) s[rt][tt] = cinit;

        __builtin_amdgcn_s_setprio(1);
        #pragma unroll
        for (int tt = 0; tt < 4; ++tt) {
          if (tt <= tm1) {
            const int kr = (tt*16 + fr) * 64;
            f16x8 kf0 = *(const f16x8*)&kt[c][kr + ((     fg*8) ^ swz)];
            f16x8 kf1 = *(const f16x8*)&kt[c][kr + ((32 + fg*8) ^ swz)];
            s[1][tt] = __builtin_amdgcn_mfma_f32_16x16x32_f16(kf0, qf[1][0], s[1][tt], 0, 0, 0);
            s[1][tt] = __builtin_amdgcn_mfma_f32_16x16x32_f16(kf1, qf[1][1], s[1][tt], 0, 0, 0);
            if (tt <= tm0) {
              s[0][tt] = __builtin_amdgcn_mfma_f32_16x16x32_f16(kf0, qf[0][0], s[0][tt], 0, 0, 0);
              s[0][tt] = __builtin_amdgcn_mfma_f32_16x16x32_f16(kf1, qf[0][1], s[0][tt], 0, 0, 0);
            }
          }
        }
        __builtin_amdgcn_s_setprio(0);

        #pragma unroll
        for (int rt = 0; rt < 2; ++rt) {
          const int tmr = rt ? tm1 : tm0;
          if (tmr < 0) continue;
          const int thr = dq + rt*16 + fr;
          #pragma unroll
          for (int tt = 0; tt < 4; ++tt) {
            union { f16x4 v; h16x2 h[2]; } pk;
            pk.v = (f16x4){};
            if (tt <= tmr) {
              float p[4];
              if (allv) {
                #pragma unroll
                for (int r = 0; r < 4; ++r) {
                  float sv = s[rt][tt][r];
                  if (!fullb) sv = (tt*16 + fg*4 + r <= thr) ? sv : -1e30f;
                  p[r] = exp2f(sv);
                }
              } else {
                int4 a4 = *(const int4*)&amb[kb + tt*16 + fg*4];
                #pragma unroll
                for (int r = 0; r < 4; ++r) {
                  float sv = s[rt][tt][r];
                  if (!fullb) sv = (tt*16 + fg*4 + r <= thr) ? sv : -1e30f;
                  float pv = exp2f(sv);
                  int mr_ = (r == 0) ? a4.x : (r == 1) ? a4.y : (r == 2) ? a4.z : a4.w;
                  p[r] = mr_ ? pv : 0.0f;
                }
              }
              pk.h[0] = __builtin_amdgcn_cvt_pkrtz(p[0], p[1]);
              pk.h[1] = __builtin_amdgcn_cvt_pkrtz(p[2], p[3]);
            }
            *(f16x4*)&plw[(rt*16 + fr) * 64 + ((tt*16 + fg*4) ^ swz)] = pk.v;
          }
        }

        __builtin_amdgcn_s_setprio(1);
        #pragma unroll
        for (int ks = 0; ks < 2; ++ks) {
          if (ks <= (tm1 >> 1)) {
            f16x8 vf[4];
            #pragma unroll
            for (int nt = 0; nt < 4; ++nt)
              vf[nt] = *(const f16x8*)&vt[c][(nt*16 + fr) * 64 +
                           ((ks*32 + fg*8) ^ swz ^ (((2*nt + (fr >> 3)) & 3) << 4))];
            #pragma unroll
            for (int rt = 0; rt < 2; ++rt) {
              const int tmr = rt ? tm1 : tm0;
              if (tmr >= 0 && ks <= (tmr >> 1)) {
                f16x8 pa = *(const f16x8*)&plw[(rt*16 + fr) * 64 + ((ks*32 + fg*8) ^ swz)];
                #pragma unroll
                for (int nt = 0; nt < 4; ++nt)
                  accO[rt][nt] = __builtin_amdgcn_mfma_f32_16x16x32_f16(pa, vf[nt], accO[rt][nt], 0, 0, 0);
                accL[rt] = __builtin_amdgcn_mfma_f32_16x16x32_f16(pa, onesf, accL[rt], 0, 0, 0);
              }
            }
          }
        }
        __builtin_amdgcn_s_setprio(0);
      }

      if (nt_ >= 0) WRITE_V(c ^ 1);
      __syncthreads();
      c ^= 1;
    }

    #pragma unroll
    for (int rt = 0; rt < 2; ++rt) {
      if (fr == 0) {
        #pragma unroll
        for (int r = 0; r < 4; ++r)
          lp[(size_t)bh * S_ + q0w + rt*16 + fg*4 + r] = accL[rt][r];
      }
      f16* Oprow = Op + (size_t)bh * (S_ * HD_);
      #pragma unroll
      for (int nt = 0; nt < 4; ++nt) {
        int col = nt*16 + fr;
        #pragma unroll
        for (int r = 0; r < 4; ++r) {
          int row = q0w + rt*16 + fg*4 + r;
          Oprow[(size_t)row * HD_ + col] = (f16)accO[rt][nt][r];
        }
      }
    }
  }

#undef STAGE_K
#undef LOAD_V
#undef WRITE_V
}

// ---------------- combine: O = (OA + OB) / (lA + lB) -> [B][S][D] ----------------
__global__ __launch_bounds__(256) void k_comb(const f16* __restrict__ OA,
                                              const f16* __restrict__ OB,
                                              const float* __restrict__ lA,
                                              const float* __restrict__ lB,
                                              f16* __restrict__ Obf) {
  int gid = blockIdx.x * 256 + threadIdx.x;    // 512K threads
  int seg = gid & 7, rowg = gid >> 3;          // rowg = bh*2048 + row
  int bh = rowg >> 11, row = rowg & 2047;
  f16x8 a  = ((const f16x8*)OA)[gid];
  f16x8 b2 = ((const f16x8*)OB)[gid];
  float inv = __builtin_amdgcn_rcpf(lA[rowg] + lB[rowg]);
  f16x8 o;
  #pragma unroll
  for (int j = 0; j < 8; ++j) o[j] = (f16)(((float)a[j] + (float)b2[j]) * inv);
  int bb = bh >> 4, hh = bh & 15;
  *(f16x8*)&Obf[((size_t)(bb * S_ + row)) * D_ + hh * 64 + seg * 8] = o;
}

extern "C" void kernel_launch(void* const* d_in, const int* in_sizes, int n_in,
                              void* d_out, int out_size, void* d_ws, size_t ws_size,
                              hipStream_t stream) {
  const float* x  = (const float*)d_in[0];
  const int*   am = (const int*)d_in[1];
  const float* Wq = (const float*)d_in[2];
  const float* bq = (const float*)d_in[3];
  const float* Wk = (const float*)d_in[4];
  const float* bk = (const float*)d_in[5];
  const float* Wv = (const float*)d_in[6];
  const float* bv = (const float*)d_in[7];
  const float* Wo = (const float*)d_in[8];
  const float* bo = (const float*)d_in[9];

  char* ws = (char*)d_ws;
  f16*   xb  = (f16*)(ws);                      // [0,8)MB  : x f16 (dead after QKV GEMM)
  f16*   wt  = (f16*)(ws + (8u  << 20));        // [8,16)MB : 4x WT f16 (wt3 LIVE till out-GEMM)
  f16*   qkv = (f16*)(ws + (16u << 20));        // [16,40)MB: Q,K,V (Q dead after attn)
  f16*   OpA = (f16*)(ws + (40u << 20));        // [40,48)MB: partial O, type A
  f16*   OpB = xb;                              // [0,8)MB  : partial O, type B (over dead xb)
  float* lpA = (float*)(ws + (8u << 20));       // over wt0 (dead after QKV)
  float* lpB = (float*)(ws + (8u << 20) + (256u << 10));
  f16*   Obf = qkv;                             // [16,24)MB: combined O (over dead Q)

  k_prep<<<8192, 256, 0, stream>>>(x, xb, Wq, Wk, Wv, Wo, wt);

  k_gemm_qkv<<<dim3(24, 32), 256, 0, stream>>>(xb, wt, bq, bk, bv, qkv);

  k_attn<<<dim3(512), 256, 0, stream>>>(qkv,
                                        qkv + (size_t)M_ * D_,
                                        qkv + 2 * (size_t)M_ * D_,
                                        am, OpA, OpB, lpA, lpB);

  k_comb<<<dim3(2048), 256, 0, stream>>>(OpA, OpB, lpA, lpB, Obf);

  k_gemm_out<<<dim3(8, 32), 256, 0, stream>>>(Obf, wt + 3 * (size_t)(D_ * D_), bo,
                                              (float*)d_out);
}

// Round 18
// 117.362 us; speedup vs baseline: 1.1897x; 1.0518x over previous
//
#include <hip/hip_runtime.h>

#define D_  1024
#define H_  16
#define HD_ 64
#define B_  2
#define S_  2048
#define M_  (B_*S_)   // 4096

typedef _Float16 f16;
typedef _Float16 f16x8 __attribute__((ext_vector_type(8)));
typedef _Float16 f16x4 __attribute__((ext_vector_type(4)));
typedef _Float16 f16x2 __attribute__((ext_vector_type(2)));
typedef __fp16   h16x2 __attribute__((ext_vector_type(2)));
typedef float    f32x4 __attribute__((ext_vector_type(4)));

#define GLOAD_LDS16(g, l) \
  __builtin_amdgcn_global_load_lds((__attribute__((address_space(1))) const void*)(g), \
                                   (__attribute__((address_space(3))) void*)(l), 16, 0, 0)

// ---------------- prep: x fp32->f16 (blocks 0..4095) + 4x W transpose (4096..8191) ----------------
__global__ void k_prep(const float* __restrict__ x, f16* __restrict__ xb,
                       const float* __restrict__ Wq, const float* __restrict__ Wk,
                       const float* __restrict__ Wv, const float* __restrict__ Wo,
                       f16* __restrict__ WT) {
  __shared__ float t[32][33];
  const int bid = blockIdx.x, tid = threadIdx.x;
  if (bid < 4096) {
    int i = bid * 256 + tid;
    float4 v = ((const float4*)x)[i];
    f16x4 o = { (f16)v.x, (f16)v.y, (f16)v.z, (f16)v.w };
    ((f16x4*)xb)[i] = o;
  } else {
    int r = bid - 4096;
    const int z = r >> 10; r &= 1023;
    const int n0 = (r & 31) * 32, k0 = (r >> 5) * 32;
    const float* W = (z == 0) ? Wq : (z == 1) ? Wk : (z == 2) ? Wv : Wo;
    f16* out = WT + (size_t)z * D_ * D_;
    const int tx = tid & 31, ty = tid >> 5;
    #pragma unroll
    for (int i = 0; i < 4; i++)
      t[ty + i*8][tx] = W[(size_t)(k0 + ty + i*8) * D_ + n0 + tx];
    __syncthreads();
    #pragma unroll
    for (int i = 0; i < 4; i++)
      out[(size_t)(n0 + ty + i*8) * D_ + k0 + tx] = (f16)t[tx][ty + i*8];
  }
}

// ---------------- GEMM: A[M][K] f16 @ (Bt[N][K])^T + bias, 2-phase dbuf ----------------
template<int MODE>
__device__ __forceinline__ void gemm_body(const f16* __restrict__ A,
                                          const f16* __restrict__ Bt,
                                          const float* __restrict__ bias,
                                          void* __restrict__ Cout) {
  __shared__ __align__(16) f16 lA[2][128 * 32];
  __shared__ __align__(16) f16 lB[2][128 * 32];
  const int tid = threadIdx.x;
  const int wv = tid >> 6, lane = tid & 63;
  const int m0 = blockIdx.y * 128, n0 = blockIdx.x * 128;
  const int fr = lane & 15, fg = lane >> 4;
  const int wm = wv >> 1, wn = wv & 1;
  const int srow = (lane >> 2), skk = (lane & 3) * 8;
  f32x4 acc[4][4] = {};

#define G_STAGE(k0_, c_) do { \
    _Pragma("unroll") \
    for (int it_ = 0; it_ < 2; ++it_) { \
      int ch_ = wv + it_ * 4; \
      int row_ = ch_ * 16 + srow; \
      GLOAD_LDS16(A  + (size_t)(m0 + row_) * D_ + (k0_) + skk, &lA[c_][ch_ * 512]); \
      GLOAD_LDS16(Bt + (size_t)(n0 + row_) * D_ + (k0_) + skk, &lB[c_][ch_ * 512]); \
    } \
  } while (0)

  G_STAGE(0, 0);
  __syncthreads();

  int c = 0;
  for (int k0 = 0; k0 < D_; k0 += 32) {
    if (k0 + 32 < D_) G_STAGE(k0 + 32, c ^ 1);
    f16x8 a[4], b[4];
    #pragma unroll
    for (int i = 0; i < 4; i++) a[i] = *(const f16x8*)&lA[c][(wm*64 + i*16 + fr) * 32 + fg * 8];
    #pragma unroll
    for (int j = 0; j < 4; j++) b[j] = *(const f16x8*)&lB[c][(wn*64 + j*16 + fr) * 32 + fg * 8];
    #pragma unroll
    for (int i = 0; i < 4; i++)
      #pragma unroll
      for (int j = 0; j < 4; j++)
        acc[i][j] = __builtin_amdgcn_mfma_f32_16x16x32_f16(a[i], b[j], acc[i][j], 0, 0, 0);
    __syncthreads();
    c ^= 1;
  }
#undef G_STAGE

  #pragma unroll
  for (int i = 0; i < 4; i++) {
    #pragma unroll
    for (int j = 0; j < 4; j++) {
      int grow0 = m0 + wm*64 + i*16 + fg*4;
      int gcol  = n0 + wn*64 + j*16 + fr;
      float bb = bias[gcol & (D_ - 1)];
      #pragma unroll
      for (int r = 0; r < 4; r++) {
        float val = acc[i][j][r] + bb;
        int grow = grow0 + r;
        if (MODE == 0) {
          int z = gcol >> 10, gl = gcol & (D_ - 1);
          int b = grow >> 11, s = grow & (S_ - 1);
          int h = gl >> 6,  hd = gl & (HD_ - 1);
          ((f16*)Cout)[(size_t)z * (M_ * D_) +
                       ((size_t)(b * H_ + h) * S_ + s) * HD_ + hd] = (f16)val;
        } else {
          ((float*)Cout)[(size_t)grow * D_ + gcol] = val;
        }
      }
    }
  }
}

__global__ __launch_bounds__(256) void k_gemm_qkv(const f16* __restrict__ A,
                                                  const f16* __restrict__ WT0,
                                                  const float* __restrict__ bq,
                                                  const float* __restrict__ bk,
                                                  const float* __restrict__ bv,
                                                  f16* __restrict__ qkv) {
  const int n0 = blockIdx.x * 128;
  const float* bias = (n0 < 1024) ? bq : (n0 < 2048) ? bk : bv;
  gemm_body<0>(A, WT0, bias, qkv);
}

__global__ __launch_bounds__(256) void k_gemm_out(const f16* __restrict__ A,
                                                  const f16* __restrict__ Bt,
                                                  const float* __restrict__ bias,
                                                  float* __restrict__ Cout) {
  gemm_body<1>(A, Bt, bias, Cout);
}

// ---------------- flash attention v10.1: unified kv schedule + raw v_exp ----------------
#define POFF 8.65617025f   // 6 * log2(e)

__global__ __launch_bounds__(256) void k_attn(const f16* __restrict__ Qh,
                                              const f16* __restrict__ Kh,
                                              const f16* __restrict__ Vh,
                                              const int* __restrict__ am,
                                              f16* __restrict__ OpA, f16* __restrict__ OpB,
                                              float* __restrict__ lpA, float* __restrict__ lpB) {
  __shared__ __align__(16) f16 kt[2][64 * 64];     // K [k][d], XOR-swizzled
  __shared__ __align__(16) f16 vt[2][64 * 64];     // V^T [d][k], 2-level XOR-swizzled
  __shared__ __align__(16) f16 pl[4][32 * 64];     // per-wave P [qrow][k], swizzled

  const int tid = threadIdx.x;
  const int wv = tid >> 6, lane = tid & 63;
  const int fr = lane & 15, fg = lane >> 4;

  const int d = blockIdx.x;             // [0,512)
  const int bh = d & 31;
  const int m  = (d >> 5) & 7;          // pair index 0..7 -> tiles (m, 15-m)
  const int typeB = d >> 8;
  const int b = bh >> 4;

  f16*   Op = typeB ? OpB : OpA;
  float* lp = typeB ? lpB : lpA;

  const f16* Qb = Qh + (size_t)bh * S_ * HD_;
  const f16* Kb = Kh + (size_t)bh * S_ * HD_;
  const f16* Vb = Vh + (size_t)bh * S_ * HD_;
  const int* amb = am + b * S_;
  f16* plw = pl[wv];

  volatile int* flag = (volatile int*)&pl[0][0];
  if (tid == 0) *flag = 1;
  __syncthreads();
  {
    int mv = 1;
    #pragma unroll
    for (int i = 0; i < 8; ++i) mv &= amb[tid * 8 + i];
    if (!mv) *flag = 0;
  }
  __syncthreads();
  const bool allv = (*flag != 0);

  const f16 qs = (f16)0.18033688f;       // 0.125 * log2(e)
  const int ksrc = 8 * ((lane & 7) ^ (lane >> 3));
  const int swz = (fr & 7) << 3;
  const int vkk = (tid >> 3) * 2, vd0 = (tid & 7) * 8;
  const int vswz2 = (tid & 3) << 4;
  const f32x4 cinit = { -POFF, -POFF, -POFF, -POFF };
  const f16 one_ = (f16)1.0f;
  const f16x8 onesf = { one_, one_, one_, one_, one_, one_, one_, one_ };

#define STAGE_K(t_, c_) do { \
    const f16* kp_ = Kb + (size_t)((t_) * 64) * HD_; \
    GLOAD_LDS16(kp_ + (size_t)((wv*2+0)*8 + (lane >> 3)) * HD_ + ksrc, &kt[c_][(wv*2+0)*512]); \
    GLOAD_LDS16(kp_ + (size_t)((wv*2+1)*8 + (lane >> 3)) * HD_ + ksrc, &kt[c_][(wv*2+1)*512]); \
  } while (0)

#define LOAD_V(t_) do { \
    const f16* vp_ = Vb + (size_t)((t_) * 64 + vkk) * HD_ + vd0; \
    vA = *(const f16x8*)vp_; vBr = *(const f16x8*)(vp_ + HD_); \
  } while (0)

#define WRITE_V(c_) do { \
    _Pragma("unroll") \
    for (int j_ = 0; j_ < 8; ++j_) { \
      f16x2 pr_ = { vA[j_], vBr[j_] }; \
      *(f16x2*)&vt[c_][(vd0 + j_) * 64 + ((vkk ^ (j_ << 3)) ^ vswz2)] = pr_; \
    } \
  } while (0)

  f16x8 vA, vBr;

  const int qts[2] = { m, 15 - m };
  int s_t0[2], s_t1[2];
  if (!typeB) {
    s_t0[0] = 0;     s_t1[0] = m + 1;
    s_t0[1] = 0;     s_t1[1] = 16 - m;
  } else {
    s_t0[0] = m + 1;  s_t1[0] = 2 * (m + 1);
    s_t0[1] = 16 - m; s_t1[1] = 2 * (16 - m);
  }

  STAGE_K(s_t0[0], 0);
  LOAD_V(s_t0[0]);
  WRITE_V(0);
  __syncthreads();

  int c = 0;
  for (int sg = 0; sg < 2; ++sg) {
    const int qt = qts[sg];
    const int q0w = qt * 128 + wv * 32;

    f16x8 qf[2][2];
    #pragma unroll
    for (int rt = 0; rt < 2; ++rt) {
      f16x8 r0 = *(const f16x8*)&Qb[(size_t)(q0w + rt*16 + fr) * HD_ + fg*8];
      f16x8 r1 = *(const f16x8*)&Qb[(size_t)(q0w + rt*16 + fr) * HD_ + 32 + fg*8];
      qf[rt][0] = r0 * qs; qf[rt][1] = r1 * qs;
    }

    f32x4 accO[2][4] = {};
    f32x4 accL[2] = {};

    for (int t = s_t0[sg]; t < s_t1[sg]; ++t) {
      int nt_ = -1;
      if (t + 1 < s_t1[sg]) nt_ = t + 1;
      else if (sg == 0)     nt_ = s_t0[1];
      if (nt_ >= 0) { STAGE_K(nt_, c ^ 1); LOAD_V(nt_); }

      const int kb = t * 64;
      const int dq = q0w - kb;
      if (dq + 31 >= 0) {
        int tm1 = (dq + 31) >> 4; if (tm1 > 3) tm1 = 3;
        int tm0 = (dq + 15) >> 4; if (tm0 > 3) tm0 = 3;
        const bool fullb = (dq >= 63);

        f32x4 s[2][4];
        #pragma unroll
        for (int rt = 0; rt < 2; ++rt)
          #pragma unroll
          for (int tt = 0; tt < 4; ++tt) s[rt][tt] = cinit;

        __builtin_amdgcn_s_setprio(1);
        #pragma unroll
        for (int tt = 0; tt < 4; ++tt) {
          if (tt <= tm1) {
            const int kr = (tt*16 + fr) * 64;
            f16x8 kf0 = *(const f16x8*)&kt[c][kr + ((     fg*8) ^ swz)];
            f16x8 kf1 = *(const f16x8*)&kt[c][kr + ((32 + fg*8) ^ swz)];
            s[1][tt] = __builtin_amdgcn_mfma_f32_16x16x32_f16(kf0, qf[1][0], s[1][tt], 0, 0, 0);
            s[1][tt] = __builtin_amdgcn_mfma_f32_16x16x32_f16(kf1, qf[1][1], s[1][tt], 0, 0, 0);
            if (tt <= tm0) {
              s[0][tt] = __builtin_amdgcn_mfma_f32_16x16x32_f16(kf0, qf[0][0], s[0][tt], 0, 0, 0);
              s[0][tt] = __builtin_amdgcn_mfma_f32_16x16x32_f16(kf1, qf[0][1], s[0][tt], 0, 0, 0);
            }
          }
        }
        __builtin_amdgcn_s_setprio(0);

        #pragma unroll
        for (int rt = 0; rt < 2; ++rt) {
          const int tmr = rt ? tm1 : tm0;
          if (tmr < 0) continue;
          const int thr = dq + rt*16 + fr;
          #pragma unroll
          for (int tt = 0; tt < 4; ++tt) {
            union { f16x4 v; h16x2 h[2]; } pk;
            pk.v = (f16x4){};
            if (tt <= tmr) {
              float p[4];
              if (allv) {
                #pragma unroll
                for (int r = 0; r < 4; ++r) {
                  float sv = s[rt][tt][r];
                  if (!fullb) sv = (tt*16 + fg*4 + r <= thr) ? sv : -1e30f;
                  p[r] = __builtin_amdgcn_exp2f(sv);
                }
              } else {
                int4 a4 = *(const int4*)&amb[kb + tt*16 + fg*4];
                #pragma unroll
                for (int r = 0; r < 4; ++r) {
                  float sv = s[rt][tt][r];
                  if (!fullb) sv = (tt*16 + fg*4 + r <= thr) ? sv : -1e30f;
                  float pv = __builtin_amdgcn_exp2f(sv);
                  int mr_ = (r == 0) ? a4.x : (r == 1) ? a4.y : (r == 2) ? a4.z : a4.w;
                  p[r] = mr_ ? pv : 0.0f;
                }
              }
              pk.h[0] = __builtin_amdgcn_cvt_pkrtz(p[0], p[1]);
              pk.h[1] = __builtin_amdgcn_cvt_pkrtz(p[2], p[3]);
            }
            *(f16x4*)&plw[(rt*16 + fr) * 64 + ((tt*16 + fg*4) ^ swz)] = pk.v;
          }
        }

        __builtin_amdgcn_s_setprio(1);
        #pragma unroll
        for (int ks = 0; ks < 2; ++ks) {
          if (ks <= (tm1 >> 1)) {
            f16x8 vf[4];
            #pragma unroll
            for (int nt = 0; nt < 4; ++nt)
              vf[nt] = *(const f16x8*)&vt[c][(nt*16 + fr) * 64 +
                           ((ks*32 + fg*8) ^ swz ^ (((2*nt + (fr >> 3)) & 3) << 4))];
            #pragma unroll
            for (int rt = 0; rt < 2; ++rt) {
              const int tmr = rt ? tm1 : tm0;
              if (tmr >= 0 && ks <= (tmr >> 1)) {
                f16x8 pa = *(const f16x8*)&plw[(rt*16 + fr) * 64 + ((ks*32 + fg*8) ^ swz)];
                #pragma unroll
                for (int nt = 0; nt < 4; ++nt)
                  accO[rt][nt] = __builtin_amdgcn_mfma_f32_16x16x32_f16(pa, vf[nt], accO[rt][nt], 0, 0, 0);
                accL[rt] = __builtin_amdgcn_mfma_f32_16x16x32_f16(pa, onesf, accL[rt], 0, 0, 0);
              }
            }
          }
        }
        __builtin_amdgcn_s_setprio(0);
      }

      if (nt_ >= 0) WRITE_V(c ^ 1);
      __syncthreads();
      c ^= 1;
    }

    #pragma unroll
    for (int rt = 0; rt < 2; ++rt) {
      if (fr == 0) {
        #pragma unroll
        for (int r = 0; r < 4; ++r)
          lp[(size_t)bh * S_ + q0w + rt*16 + fg*4 + r] = accL[rt][r];
      }
      f16* Oprow = Op + (size_t)bh * (S_ * HD_);
      #pragma unroll
      for (int nt = 0; nt < 4; ++nt) {
        int col = nt*16 + fr;
        #pragma unroll
        for (int r = 0; r < 4; ++r) {
          int row = q0w + rt*16 + fg*4 + r;
          Oprow[(size_t)row * HD_ + col] = (f16)accO[rt][nt][r];
        }
      }
    }
  }

#undef STAGE_K
#undef LOAD_V
#undef WRITE_V
}

// ---------------- combine: O = (OA + OB) / (lA + lB) -> [B][S][D] ----------------
__global__ __launch_bounds__(256) void k_comb(const f16* __restrict__ OA,
                                              const f16* __restrict__ OB,
                                              const float* __restrict__ lA,
                                              const float* __restrict__ lB,
                                              f16* __restrict__ Obf) {
  int gid = blockIdx.x * 256 + threadIdx.x;    // 512K threads
  int seg = gid & 7, rowg = gid >> 3;          // rowg = bh*2048 + row
  int bh = rowg >> 11, row = rowg & 2047;
  f16x8 a  = ((const f16x8*)OA)[gid];
  f16x8 b2 = ((const f16x8*)OB)[gid];
  float inv = __builtin_amdgcn_rcpf(lA[rowg] + lB[rowg]);
  f16x8 o;
  #pragma unroll
  for (int j = 0; j < 8; ++j) o[j] = (f16)(((float)a[j] + (float)b2[j]) * inv);
  int bb = bh >> 4, hh = bh & 15;
  *(f16x8*)&Obf[((size_t)(bb * S_ + row)) * D_ + hh * 64 + seg * 8] = o;
}

extern "C" void kernel_launch(void* const* d_in, const int* in_sizes, int n_in,
                              void* d_out, int out_size, void* d_ws, size_t ws_size,
                              hipStream_t stream) {
  const float* x  = (const float*)d_in[0];
  const int*   am = (const int*)d_in[1];
  const float* Wq = (const float*)d_in[2];
  const float* bq = (const float*)d_in[3];
  const float* Wk = (const float*)d_in[4];
  const float* bk = (const float*)d_in[5];
  const float* Wv = (const float*)d_in[6];
  const float* bv = (const float*)d_in[7];
  const float* Wo = (const float*)d_in[8];
  const float* bo = (const float*)d_in[9];

  char* ws = (char*)d_ws;
  f16*   xb  = (f16*)(ws);                      // [0,8)MB  : x f16 (dead after QKV GEMM)
  f16*   wt  = (f16*)(ws + (8u  << 20));        // [8,16)MB : 4x WT f16 (wt3 LIVE till out-GEMM)
  f16*   qkv = (f16*)(ws + (16u << 20));        // [16,40)MB: Q,K,V (Q dead after attn)
  f16*   OpA = (f16*)(ws + (40u << 20));        // [40,48)MB: partial O, type A
  f16*   OpB = xb;                              // [0,8)MB  : partial O, type B (over dead xb)
  float* lpA = (float*)(ws + (8u << 20));       // over wt0 (dead after QKV)
  float* lpB = (float*)(ws + (8u << 20) + (256u << 10));
  f16*   Obf = qkv;                             // [16,24)MB: combined O (over dead Q)

  k_prep<<<8192, 256, 0, stream>>>(x, xb, Wq, Wk, Wv, Wo, wt);

  k_gemm_qkv<<<dim3(24, 32), 256, 0, stream>>>(xb, wt, bq, bk, bv, qkv);

  k_attn<<<dim3(512), 256, 0, stream>>>(qkv,
                                        qkv + (size_t)M_ * D_,
                                        qkv + 2 * (size_t)M_ * D_,
                                        am, OpA, OpB, lpA, lpB);

  k_comb<<<dim3(2048), 256, 0, stream>>>(OpA, OpB, lpA, lpB, Obf);

  k_gemm_out<<<dim3(8, 32), 256, 0, stream>>>(Obf, wt + 3 * (size_t)(D_ * D_), bo,
                                              (float*)d_out);
}